// Round 12
// baseline (974.971 us; speedup 1.0000x reference)
//
#include <hip/hip_runtime.h>
#include <hip/hip_fp16.h>

#define DEV_INLINE __device__ __forceinline__

static const int SCAN_B = 512;

// clang ext_vector types (accepted by __builtin_nontemporal_*)
typedef unsigned uvec4 __attribute__((ext_vector_type(4)));
typedef unsigned uvec2 __attribute__((ext_vector_type(2)));
typedef float    fvec4 __attribute__((ext_vector_type(4)));

DEV_INLINE int   ntload_i(const int* p)  { return __builtin_nontemporal_load(p); }
DEV_INLINE uint4 ntload_u4(const uint4* p) {
    uvec4 v = __builtin_nontemporal_load((const uvec4*)p);
    return make_uint4(v.x, v.y, v.z, v.w);
}
DEV_INLINE uint2 ntload_u2(const uint2* p) {
    uvec2 v = __builtin_nontemporal_load((const uvec2*)p);
    return make_uint2(v.x, v.y);
}
DEV_INLINE float4 ntload_f4(const float4* p) {
    fvec4 v = __builtin_nontemporal_load((const fvec4*)p);
    return make_float4(v.x, v.y, v.z, v.w);
}
DEV_INLINE float ntload_f(const float* p) { return __builtin_nontemporal_load(p); }
DEV_INLINE unsigned short ntload_h(const unsigned short* p) { return __builtin_nontemporal_load(p); }
DEV_INLINE void ntstore_u4(uint4* p, uint4 v) {
    uvec4 t; t.x = v.x; t.y = v.y; t.z = v.z; t.w = v.w;
    __builtin_nontemporal_store(t, (uvec4*)p);
}
DEV_INLINE void ntstore_f4(float4* p, float4 v) {
    fvec4 t; t.x = v.x; t.y = v.y; t.z = v.z; t.w = v.w;
    __builtin_nontemporal_store(t, (fvec4*)p);
}

DEV_INLINE int lower_bound_i(const int* __restrict__ a, int n, int v) {
    int lo = 0, hi = n;
    while (lo < hi) { int m = (lo + hi) >> 1; if (a[m] < v) lo = m + 1; else hi = m; }
    return lo;
}

// h[0:16] += 4 features * W rows (wave-uniform W -> scalar loads)
DEV_INLINE void fma4a(float (&h)[16], const float* __restrict__ W,
                      float a0, float a1, float a2, float a3) {
#pragma unroll
    for (int j = 0; j < 16; j++) h[j] = fmaf(a0, W[0 * 16 + j], h[j]);
#pragma unroll
    for (int j = 0; j < 16; j++) h[j] = fmaf(a1, W[1 * 16 + j], h[j]);
#pragma unroll
    for (int j = 0; j < 16; j++) h[j] = fmaf(a2, W[2 * 16 + j], h[j]);
#pragma unroll
    for (int j = 0; j < 16; j++) h[j] = fmaf(a3, W[3 * 16 + j], h[j]);
}
DEV_INLINE void fma4(float (&h)[16], const float* __restrict__ W, float4 a) {
    fma4a(h, W, a.x, a.y, a.z, a.w);
}

DEV_INLINE unsigned f2h2(float a, float b) {
    __half2 h = __floats2half2_rn(a, b);
    return *reinterpret_cast<unsigned*>(&h);
}
DEV_INLINE float2 h2f2(unsigned u) {
    __half2 h;
    *reinterpret_cast<unsigned*>(&h) = u;
    return __half22float2(h);
}
DEV_INLINE void unpack8(uint4 u, float* f) {
    float2 a = h2f2(u.x), b = h2f2(u.y), c = h2f2(u.z), d = h2f2(u.w);
    f[0]=a.x; f[1]=a.y; f[2]=b.x; f[3]=b.y; f[4]=c.x; f[5]=c.y; f[6]=d.x; f[7]=d.y;
}
DEV_INLINE uint4 pack8(const float* f) {
    return make_uint4(f2h2(f[0],f[1]), f2h2(f[2],f[3]), f2h2(f[4],f[5]), f2h2(f[6],f[7]));
}

// ========================= CSR build (once per launch) ======================
__global__ void hist_kernel(const int* __restrict__ receivers, int n_edges,
                            int* __restrict__ cnt) {
    int i = blockIdx.x * blockDim.x + threadIdx.x;
    if (i < n_edges) atomicAdd(&cnt[receivers[i]], 1);
}

__global__ __launch_bounds__(SCAN_B)
void scan_block_kernel(const int* __restrict__ cnt, int n,
                       int* __restrict__ scan_tmp, int* __restrict__ blk_sum) {
    __shared__ int s[SCAN_B];
    int tid = threadIdx.x;
    int i = blockIdx.x * SCAN_B + tid;
    int v = (i < n) ? cnt[i] : 0;
    s[tid] = v;
    __syncthreads();
    for (int off = 1; off < SCAN_B; off <<= 1) {
        int t = (tid >= off) ? s[tid - off] : 0;
        __syncthreads();
        s[tid] += t;
        __syncthreads();
    }
    if (i < n) scan_tmp[i] = s[tid];
    if (tid == SCAN_B - 1) blk_sum[blockIdx.x] = s[tid];
}

__global__ __launch_bounds__(1024)
void scan_top_kernel(int* __restrict__ blk_sum, int nb, int* __restrict__ blk_off) {
    __shared__ int s[1024];
    int tid = threadIdx.x;
    int v = (tid < nb) ? blk_sum[tid] : 0;
    s[tid] = v;
    __syncthreads();
    for (int off = 1; off < 1024; off <<= 1) {
        int t = (tid >= off) ? s[tid - off] : 0;
        __syncthreads();
        s[tid] += t;
        __syncthreads();
    }
    if (tid < nb) blk_off[tid] = s[tid] - v;   // exclusive
}

__global__ __launch_bounds__(SCAN_B)
void scan_finalize_kernel(const int* __restrict__ cnt, const int* __restrict__ scan_tmp,
                          const int* __restrict__ blk_off, int n,
                          int* __restrict__ row_ptr, int* __restrict__ running) {
    int i = blockIdx.x * SCAN_B + threadIdx.x;
    if (i >= n) return;
    int incl = scan_tmp[i] + blk_off[i / SCAN_B];
    row_ptr[i + 1] = incl;
    running[i] = incl - cnt[i];
    if (i == 0) row_ptr[0] = 0;
}

__global__ void fill_kernel(const int* __restrict__ receivers, int n_edges,
                            int* __restrict__ running, int* __restrict__ col_idx) {
    int e = blockIdx.x * blockDim.x + threadIdx.x;
    if (e >= n_edges) return;
    int pos = atomicAdd(&running[receivers[e]], 1);
    col_idx[pos] = e;
}

// ---- Per-pass precompute: node projections (f16) + fused global MLP --------
__global__ __launch_bounds__(256)
void node_proj_kernel(const float* __restrict__ nodes_in,
                      const float* __restrict__ glob_prev,
                      float* __restrict__ glob_cur,          // null on pass 0
                      float* __restrict__ gsum_e, float* __restrict__ gsum_n,
                      const int* __restrict__ edge_gid, int n_edges,
                      const int* __restrict__ node_gid, int n_nodes,
                      const float* __restrict__ gW1, const float* __restrict__ gB1,
                      const float* __restrict__ gW2, const float* __restrict__ gB2,
                      const float* __restrict__ gW3, const float* __restrict__ gB3,
                      const float* __restrict__ eW1, const float* __restrict__ eB1,
                      const float* __restrict__ nW1, const float* __restrict__ nB1,
                      __half* __restrict__ proj,
                      float* __restrict__ biasE, float* __restrict__ biasN,
                      int n_graph) {
    const int n0 = blockIdx.x * 256 + threadIdx.x;
    const int n  = min(n0, n_nodes - 1);
    const float4* pn = (const float4*)nodes_in + (size_t)n * 8;
    float4 xn[8];
#pragma unroll
    for (int q = 0; q < 8; q++) xn[q] = pn[q];

    float hr[16], hs[16];
#pragma unroll
    for (int j = 0; j < 16; j++) { hr[j] = 0.0f; hs[j] = 0.0f; }
#pragma unroll
    for (int q = 0; q < 8; q++) fma4(hr, eW1 + (32 + q * 4) * 16, xn[q]);
#pragma unroll
    for (int q = 0; q < 8; q++) fma4(hs, eW1 + (64 + q * 4) * 16, xn[q]);

    if (n0 < n_nodes) {
        uint4* po = (uint4*)(proj + (size_t)n0 * 32);
        po[0] = pack8(hr);
        po[1] = pack8(hr + 8);
        po[2] = pack8(hs);
        po[3] = pack8(hs + 8);
    }

    if (blockIdx.x == 0) {
        const int g = threadIdx.x;
        float gval[16];
        if (g < n_graph) {
            if (glob_cur) {
                int ecnt = lower_bound_i(edge_gid, n_edges, g + 1) - lower_bound_i(edge_gid, n_edges, g);
                int ncnt = lower_bound_i(node_gid, n_nodes, g + 1) - lower_bound_i(node_gid, n_nodes, g);
                float inv_e = 1.0f / fmaxf((float)ecnt, 1.0f);
                float inv_n = 1.0f / fmaxf((float)ncnt, 1.0f);
                float h1[16];
#pragma unroll
                for (int j = 0; j < 16; j++) h1[j] = gB1[j];
                float x[32];
#pragma unroll
                for (int q = 0; q < 8; q++) {
                    float4 v = ((const float4*)gsum_e)[(size_t)g * 8 + q];
                    x[q*4+0]=v.x*inv_e; x[q*4+1]=v.y*inv_e; x[q*4+2]=v.z*inv_e; x[q*4+3]=v.w*inv_e;
                }
#pragma unroll
                for (int k = 0; k < 32; k++)
#pragma unroll
                    for (int j = 0; j < 16; j++) h1[j] = fmaf(x[k], gW1[k * 16 + j], h1[j]);
#pragma unroll
                for (int q = 0; q < 8; q++) {
                    float4 v = ((const float4*)gsum_n)[(size_t)g * 8 + q];
                    x[q*4+0]=v.x*inv_n; x[q*4+1]=v.y*inv_n; x[q*4+2]=v.z*inv_n; x[q*4+3]=v.w*inv_n;
                }
#pragma unroll
                for (int k = 0; k < 32; k++)
#pragma unroll
                    for (int j = 0; j < 16; j++) h1[j] = fmaf(x[k], gW1[(32 + k) * 16 + j], h1[j]);
                float xg[16];
#pragma unroll
                for (int q = 0; q < 4; q++) {
                    float4 v = ((const float4*)glob_prev)[(size_t)g * 4 + q];
                    xg[q*4+0]=v.x; xg[q*4+1]=v.y; xg[q*4+2]=v.z; xg[q*4+3]=v.w;
                }
#pragma unroll
                for (int k = 0; k < 16; k++)
#pragma unroll
                    for (int j = 0; j < 16; j++) h1[j] = fmaf(xg[k], gW1[(64 + k) * 16 + j], h1[j]);
                float x2[16];
#pragma unroll
                for (int j = 0; j < 16; j++) x2[j] = fmaxf(h1[j], 0.0f);
                float h2[16];
#pragma unroll
                for (int j = 0; j < 16; j++) h2[j] = gB2[j];
#pragma unroll
                for (int k = 0; k < 16; k++)
#pragma unroll
                    for (int j = 0; j < 16; j++) h2[j] = fmaf(x2[k], gW2[k * 16 + j], h2[j]);
                float x3[16];
#pragma unroll
                for (int j = 0; j < 16; j++) x3[j] = fmaxf(h2[j], 0.0f);
#pragma unroll
                for (int j = 0; j < 16; j++) gval[j] = gB3[j];
#pragma unroll
                for (int k = 0; k < 16; k++)
#pragma unroll
                    for (int j = 0; j < 16; j++) gval[j] = fmaf(x3[k], gW3[k * 16 + j], gval[j]);
#pragma unroll
                for (int j = 0; j < 16; j++) glob_cur[g * 16 + j] = gval[j];
            } else {
#pragma unroll
                for (int j = 0; j < 16; j++) gval[j] = glob_prev[g * 16 + j];
            }
        }
        __syncthreads();   // gsum reads complete before zeroing
        for (int i = threadIdx.x; i < n_graph * 32; i += 256) {
            gsum_e[i] = 0.0f;
            gsum_n[i] = 0.0f;
        }
        if (g < n_graph) {
            float he[16], hn[16];
#pragma unroll
            for (int j = 0; j < 16; j++) { he[j] = eB1[j]; hn[j] = nB1[j]; }
#pragma unroll
            for (int k = 0; k < 16; k++)
#pragma unroll
                for (int j = 0; j < 16; j++) he[j] = fmaf(gval[k], eW1[(96 + k) * 16 + j], he[j]);
#pragma unroll
            for (int k = 0; k < 16; k++)
#pragma unroll
                for (int j = 0; j < 16; j++) hn[j] = fmaf(gval[k], nW1[(64 + k) * 16 + j], hn[j]);
#pragma unroll
            for (int j = 0; j < 16; j++) biasE[g * 16 + j] = he[j];
#pragma unroll
            for (int j = 0; j < 16; j++) biasN[g * 16 + j] = hn[j];
        }
    }
}

// ---------------- Edge block: 112 -> 16 -> 16 -> 32 (templated I/O) ---------
// Streaming traffic (edges in/out, index arrays) is non-temporal so the
// per-XCD L2 retains the proj/bias gather tables.
template<bool INH, bool OUTH>
__global__ __launch_bounds__(256)
void edge_block_kernel(const void* __restrict__ edges_in_v,
                       const __half* __restrict__ proj,
                       const float* __restrict__ biasE,
                       const int* __restrict__ senders,
                       const int* __restrict__ receivers,
                       const int* __restrict__ edge_gid,
                       const float* __restrict__ W1,
                       const float* __restrict__ W2, const float* __restrict__ B2,
                       const float* __restrict__ W3, const float* __restrict__ B3,
                       void* __restrict__ edges_out_v,
                       int n_edges) {
    const int e0 = blockIdx.x * 256 + threadIdx.x;
    const int e  = min(e0, n_edges - 1);

    const int rr = ntload_i(receivers + e);
    const int ss = ntload_i(senders + e);
    const int gg = ntload_i(edge_gid + e);

    float xe[32];
    if (INH) {
        const uint4* pe = (const uint4*)((const __half*)edges_in_v + (size_t)e * 32);
        uint4 u0 = ntload_u4(pe + 0), u1 = ntload_u4(pe + 1);
        uint4 u2 = ntload_u4(pe + 2), u3 = ntload_u4(pe + 3);
        unpack8(u0, xe); unpack8(u1, xe + 8); unpack8(u2, xe + 16); unpack8(u3, xe + 24);
    } else {
        const float4* pe = (const float4*)edges_in_v + (size_t)e * 8;
#pragma unroll
        for (int q = 0; q < 8; q++) {
            float4 v = ntload_f4(pe + q);
            xe[q*4+0]=v.x; xe[q*4+1]=v.y; xe[q*4+2]=v.z; xe[q*4+3]=v.w;
        }
    }

    const uint4*  pr = (const uint4*)(proj + (size_t)rr * 32);        // halves [0:16)
    const uint4*  ps = (const uint4*)(proj + (size_t)ss * 32 + 16);   // halves [16:32)
    const float4* pb = (const float4*)biasE + (size_t)gg * 4;

    uint4 r0 = pr[0], r1 = pr[1];
    uint4 s0 = ps[0], s1 = ps[1];
    float4 xb[4];
#pragma unroll
    for (int q = 0; q < 4; q++) xb[q] = pb[q];

    float r[16], s[16];
    unpack8(r0, r); unpack8(r1, r + 8);
    unpack8(s0, s); unpack8(s1, s + 8);

    float h1[16];
#pragma unroll
    for (int q = 0; q < 4; q++) {
        h1[q*4+0] = xb[q].x + r[q*4+0] + s[q*4+0];
        h1[q*4+1] = xb[q].y + r[q*4+1] + s[q*4+1];
        h1[q*4+2] = xb[q].z + r[q*4+2] + s[q*4+2];
        h1[q*4+3] = xb[q].w + r[q*4+3] + s[q*4+3];
    }
#pragma unroll
    for (int q = 0; q < 8; q++)
        fma4a(h1, W1 + (q * 4) * 16, xe[q*4+0], xe[q*4+1], xe[q*4+2], xe[q*4+3]);

    float x2[16];
#pragma unroll
    for (int j = 0; j < 16; j++) x2[j] = fmaxf(h1[j], 0.0f);
    float h2[16];
#pragma unroll
    for (int j = 0; j < 16; j++) h2[j] = B2[j];
#pragma unroll
    for (int k = 0; k < 16; k++)
#pragma unroll
        for (int j = 0; j < 16; j++) h2[j] = fmaf(x2[k], W2[k * 16 + j], h2[j]);

    float x3[16];
#pragma unroll
    for (int j = 0; j < 16; j++) x3[j] = fmaxf(h2[j], 0.0f);
    float o[32];
#pragma unroll
    for (int j = 0; j < 32; j++) o[j] = B3[j];
#pragma unroll
    for (int k = 0; k < 16; k++)
#pragma unroll
        for (int j = 0; j < 32; j++)
            o[j] = fmaf(x3[k], W3[k * 32 + j], o[j]);

    if (e0 < n_edges) {
        if (OUTH) {
            uint4* eo = (uint4*)((__half*)edges_out_v + (size_t)e0 * 32);
            ntstore_u4(eo + 0, pack8(o));
            ntstore_u4(eo + 1, pack8(o + 8));
            ntstore_u4(eo + 2, pack8(o + 16));
            ntstore_u4(eo + 3, pack8(o + 24));
        } else {
            float4* eo = (float4*)edges_out_v + (size_t)e0 * 8;
#pragma unroll
            for (int j4 = 0; j4 < 8; j4++)
                ntstore_f4(eo + j4, make_float4(o[j4*4+0], o[j4*4+1], o[j4*4+2], o[j4*4+3]));
        }
    }
}

// -------- Fused edge-consumer: per-graph sums + CSR receiver aggregation ----
// Blocks [0, n_graph*16): graph-sum role (sorted gid ranges).
// Blocks [n_graph*16, ...): agg role (8 lanes per node via CSR).
template<bool INH>
__global__ __launch_bounds__(256)
void edge_consume_kernel(const void* __restrict__ edges_data_v,
                         const int* __restrict__ gid, int n_edges,
                         float* __restrict__ gsum,
                         const int* __restrict__ col_idx,
                         const int* __restrict__ row_ptr,
                         float* __restrict__ agg_mean, int n_nodes, int n_graph) {
    __shared__ float red[256];
    const int GS_BLOCKS = n_graph * 16;

    if ((int)blockIdx.x < GS_BLOCKS) {
        int g = blockIdx.x >> 4;
        int s = blockIdx.x & 15;
        int lo = lower_bound_i(gid, n_edges, g);
        int hi = lower_bound_i(gid, n_edges, g + 1);
        int len = hi - lo;
        int chunk = (len + 15) / 16;
        int rlo = lo + s * chunk;
        int rhi = min(rlo + chunk, hi);

        int c = threadIdx.x & 31;
        int rg = threadIdx.x >> 5;   // 8 row-groups
        float acc = 0.0f;
        for (int r = rlo + rg; r < rhi; r += 8) {
            if (INH) {
                unsigned short u = ntload_h((const unsigned short*)edges_data_v + (size_t)r * 32 + c);
                __half hh; *reinterpret_cast<unsigned short*>(&hh) = u;
                acc += __half2float(hh);
            } else {
                acc += ntload_f((const float*)edges_data_v + (size_t)r * 32 + c);
            }
        }
        red[threadIdx.x] = acc;
        __syncthreads();
        if (threadIdx.x < 32) {
            float ssum = 0.0f;
#pragma unroll
            for (int i = 0; i < 8; i++) ssum += red[i * 32 + threadIdx.x];
            atomicAdd(&gsum[g * 32 + threadIdx.x], ssum);
        }
    } else {
        int bb = blockIdx.x - GS_BLOCKS;
        int node = bb * 32 + (threadIdx.x >> 3);
        int lane = threadIdx.x & 7;
        if (node >= n_nodes) return;
        int lo = row_ptr[node], hi = row_ptr[node + 1];
        float4 acc = make_float4(0.f, 0.f, 0.f, 0.f);
        for (int e = lo; e < hi; e++) {
            int idx = ntload_i(col_idx + e);
            if (INH) {
                uint2 u = ntload_u2((const uint2*)((const __half*)edges_data_v + (size_t)idx * 32 + lane * 4));
                float2 a = h2f2(u.x), b = h2f2(u.y);
                acc.x += a.x; acc.y += a.y; acc.z += b.x; acc.w += b.y;
            } else {
                float4 v = ntload_f4((const float4*)((const float*)edges_data_v + (size_t)idx * 32) + lane);
                acc.x += v.x; acc.y += v.y; acc.z += v.z; acc.w += v.w;
            }
        }
        float inv = 1.0f / fmaxf((float)(hi - lo), 1.0f);
        ((float4*)(agg_mean + (size_t)node * 32))[lane] =
            make_float4(acc.x * inv, acc.y * inv, acc.z * inv, acc.w * inv);
    }
}

// ---------------- Node block: 80 -> 16 -> 16 -> 32 --------------------------
__global__ __launch_bounds__(256)
void node_block_kernel(const float* __restrict__ agg_mean,
                       const float* __restrict__ nodes_in,
                       const float* __restrict__ biasN,
                       const int* __restrict__ node_gid,
                       const float* __restrict__ W1,
                       const float* __restrict__ W2, const float* __restrict__ B2,
                       const float* __restrict__ W3, const float* __restrict__ B3,
                       float* __restrict__ nodes_out,
                       int n_nodes) {
    const int n0 = blockIdx.x * 256 + threadIdx.x;
    const int n  = min(n0, n_nodes - 1);
    const int gg = node_gid[n];

    const float4* pa = (const float4*)agg_mean + (size_t)n * 8;
    const float4* pn = (const float4*)nodes_in + (size_t)n * 8;
    const float4* pb = (const float4*)biasN + (size_t)gg * 4;

    float4 xa[8], xn[8], xb[4];
#pragma unroll
    for (int q = 0; q < 8; q++) xa[q] = pa[q];
#pragma unroll
    for (int q = 0; q < 8; q++) xn[q] = pn[q];
#pragma unroll
    for (int q = 0; q < 4; q++) xb[q] = pb[q];

    float h1[16];
#pragma unroll
    for (int q = 0; q < 4; q++) {
        h1[q*4+0] = xb[q].x; h1[q*4+1] = xb[q].y; h1[q*4+2] = xb[q].z; h1[q*4+3] = xb[q].w;
    }
#pragma unroll
    for (int q = 0; q < 8; q++) fma4(h1, W1 + (q * 4) * 16, xa[q]);
#pragma unroll
    for (int q = 0; q < 8; q++) fma4(h1, W1 + (32 + q * 4) * 16, xn[q]);

    float x2[16];
#pragma unroll
    for (int j = 0; j < 16; j++) x2[j] = fmaxf(h1[j], 0.0f);
    float h2[16];
#pragma unroll
    for (int j = 0; j < 16; j++) h2[j] = B2[j];
#pragma unroll
    for (int k = 0; k < 16; k++)
#pragma unroll
        for (int j = 0; j < 16; j++) h2[j] = fmaf(x2[k], W2[k * 16 + j], h2[j]);

    float x3[16];
#pragma unroll
    for (int j = 0; j < 16; j++) x3[j] = fmaxf(h2[j], 0.0f);
    float o[32];
#pragma unroll
    for (int j = 0; j < 32; j++) o[j] = B3[j];
#pragma unroll
    for (int k = 0; k < 16; k++)
#pragma unroll
        for (int j = 0; j < 32; j++)
            o[j] = fmaf(x3[k], W3[k * 32 + j], o[j]);

    if (n0 < n_nodes) {
        float4* no = (float4*)(nodes_out + (size_t)n0 * 32);
#pragma unroll
        for (int j4 = 0; j4 < 8; j4++)
            no[j4] = make_float4(o[j4*4+0], o[j4*4+1], o[j4*4+2], o[j4*4+3]);
    }
}

// ---------------- Per-graph sums over sorted gid ranges (node side) ---------
__global__ __launch_bounds__(256)
void graph_sum_kernel(const float* __restrict__ x, const int* __restrict__ gid,
                      int n_rows, float* __restrict__ sums, int splits) {
    int g = blockIdx.x / splits;
    int s = blockIdx.x % splits;
    int lo = lower_bound_i(gid, n_rows, g);
    int hi = lower_bound_i(gid, n_rows, g + 1);
    int len = hi - lo;
    int chunk = (len + splits - 1) / splits;
    int rlo = lo + s * chunk;
    int rhi = min(rlo + chunk, hi);

    int c = threadIdx.x & 31;
    int rg = threadIdx.x >> 5;
    float acc = 0.0f;
    for (int r = rlo + rg; r < rhi; r += 8)
        acc += x[(size_t)r * 32 + c];

    __shared__ float red[256];
    red[threadIdx.x] = acc;
    __syncthreads();
    if (threadIdx.x < 32) {
        float ssum = 0.0f;
#pragma unroll
        for (int i = 0; i < 8; i++) ssum += red[i * 32 + threadIdx.x];
        atomicAdd(&sums[g * 32 + threadIdx.x], ssum);
    }
}

// ---------------- Global block (final pass only) -----------------------------
__global__ __launch_bounds__(64)
void global_block_kernel(const float* __restrict__ gsum_e,
                         const float* __restrict__ gsum_n,
                         const float* __restrict__ glob_in,
                         const int* __restrict__ edge_gid, int n_edges,
                         const int* __restrict__ node_gid, int n_nodes,
                         const float* __restrict__ W1, const float* __restrict__ B1,
                         const float* __restrict__ W2, const float* __restrict__ B2,
                         const float* __restrict__ W3, const float* __restrict__ B3,
                         float* __restrict__ glob_out, int n_graph) {
    const int g0 = threadIdx.x;
    const int g  = min(g0, n_graph - 1);

    int ecnt = lower_bound_i(edge_gid, n_edges, g + 1) - lower_bound_i(edge_gid, n_edges, g);
    int ncnt = lower_bound_i(node_gid, n_nodes, g + 1) - lower_bound_i(node_gid, n_nodes, g);
    float inv_e = 1.0f / fmaxf((float)ecnt, 1.0f);
    float inv_n = 1.0f / fmaxf((float)ncnt, 1.0f);

    float h1[16];
#pragma unroll
    for (int j = 0; j < 16; j++) h1[j] = B1[j];

    {
        float x[32];
#pragma unroll
        for (int q = 0; q < 8; q++) {
            float4 v = ((const float4*)gsum_e)[(size_t)g * 8 + q];
            x[q*4+0]=v.x*inv_e; x[q*4+1]=v.y*inv_e; x[q*4+2]=v.z*inv_e; x[q*4+3]=v.w*inv_e;
        }
#pragma unroll
        for (int k = 0; k < 32; k++)
#pragma unroll
            for (int j = 0; j < 16; j++) h1[j] = fmaf(x[k], W1[k * 16 + j], h1[j]);
#pragma unroll
        for (int q = 0; q < 8; q++) {
            float4 v = ((const float4*)gsum_n)[(size_t)g * 8 + q];
            x[q*4+0]=v.x*inv_n; x[q*4+1]=v.y*inv_n; x[q*4+2]=v.z*inv_n; x[q*4+3]=v.w*inv_n;
        }
#pragma unroll
        for (int k = 0; k < 32; k++)
#pragma unroll
            for (int j = 0; j < 16; j++) h1[j] = fmaf(x[k], W1[(32 + k) * 16 + j], h1[j]);
    }
    {
        float xg[16];
#pragma unroll
        for (int q = 0; q < 4; q++) {
            float4 v = ((const float4*)glob_in)[(size_t)g * 4 + q];
            xg[q*4+0]=v.x; xg[q*4+1]=v.y; xg[q*4+2]=v.z; xg[q*4+3]=v.w;
        }
#pragma unroll
        for (int k = 0; k < 16; k++)
#pragma unroll
            for (int j = 0; j < 16; j++) h1[j] = fmaf(xg[k], W1[(64 + k) * 16 + j], h1[j]);
    }

    float x2[16];
#pragma unroll
    for (int j = 0; j < 16; j++) x2[j] = fmaxf(h1[j], 0.0f);
    float h2[16];
#pragma unroll
    for (int j = 0; j < 16; j++) h2[j] = B2[j];
#pragma unroll
    for (int k = 0; k < 16; k++)
#pragma unroll
        for (int j = 0; j < 16; j++) h2[j] = fmaf(x2[k], W2[k * 16 + j], h2[j]);

    float x3[16];
#pragma unroll
    for (int j = 0; j < 16; j++) x3[j] = fmaxf(h2[j], 0.0f);
    float o[16];
#pragma unroll
    for (int j = 0; j < 16; j++) o[j] = B3[j];
#pragma unroll
    for (int k = 0; k < 16; k++)
#pragma unroll
        for (int j = 0; j < 16; j++) o[j] = fmaf(x3[k], W3[k * 16 + j], o[j]);

    if (g0 < n_graph) {
#pragma unroll
        for (int j = 0; j < 16; j++) glob_out[g0 * 16 + j] = o[j];
    }
}

extern "C" void kernel_launch(void* const* d_in, const int* in_sizes, int n_in,
                              void* d_out, int out_size, void* d_ws, size_t ws_size,
                              hipStream_t stream) {
    const float* d_nodes = (const float*)d_in[0];
    const float* d_edges = (const float*)d_in[1];
    const float* d_glob  = (const float*)d_in[2];
    const int* senders   = (const int*)d_in[3];
    const int* receivers = (const int*)d_in[4];
    const int* node_gid  = (const int*)d_in[5];
    const int* edge_gid  = (const int*)d_in[6];
    const float* e_w1 = (const float*)d_in[7];
    const float* e_b1 = (const float*)d_in[8];
    const float* e_w2 = (const float*)d_in[9];
    const float* e_b2 = (const float*)d_in[10];
    const float* e_w3 = (const float*)d_in[11];
    const float* e_b3 = (const float*)d_in[12];
    const float* n_w1 = (const float*)d_in[13];
    const float* n_b1 = (const float*)d_in[14];
    const float* n_w2 = (const float*)d_in[15];
    const float* n_b2 = (const float*)d_in[16];
    const float* n_w3 = (const float*)d_in[17];
    const float* n_b3 = (const float*)d_in[18];
    const float* g_w1 = (const float*)d_in[19];
    const float* g_b1 = (const float*)d_in[20];
    const float* g_w2 = (const float*)d_in[21];
    const float* g_b2 = (const float*)d_in[22];
    const float* g_w3 = (const float*)d_in[23];
    const float* g_b3 = (const float*)d_in[24];

    const int n_nodes = in_sizes[0] / 32;
    const int n_edges = in_sizes[1] / 32;
    const int n_graph = in_sizes[2] / 16;

    float* out_nodes = (float*)d_out;                        // n_nodes*32
    float* out_edges = out_nodes + (size_t)n_nodes * 32;     // n_edges*32
    float* out_glob  = out_edges + (size_t)n_edges * 32;     // n_graph*16

    float* ws = (float*)d_ws;
    float* ws_edges = ws;  ws += (size_t)n_edges * 32;       // reused as 2x f16 edge buffers
    float* ws_nodes = ws;  ws += (size_t)n_nodes * 32;
    float* nscratch = ws;  ws += (size_t)n_nodes * 32;       // proj(f16) THEN agg_mean(f32)
    float* gA       = ws;  ws += (size_t)n_graph * 16;
    float* gB       = ws;  ws += (size_t)n_graph * 16;
    float* gsum_e   = ws;  ws += (size_t)n_graph * 32;
    float* gsum_n   = ws;  ws += (size_t)n_graph * 32;
    float* biasE    = ws;  ws += (size_t)n_graph * 16;
    float* biasN    = ws;  ws += (size_t)n_graph * 16;

    __half* eh0 = (__half*)ws_edges;                         // n_edges*32 halves
    __half* eh1 = eh0 + (size_t)n_edges * 32;                // n_edges*32 halves

    int* wi = (int*)ws;
    int* cnt      = wi;  wi += n_nodes;
    int* row_ptr  = wi;  wi += n_nodes + 1;
    int* running  = wi;  wi += n_nodes;
    int* scan_tmp = wi;  wi += n_nodes;
    int* col_idx  = wi;  wi += n_edges;
    int* blk_sum  = wi;  wi += 1024;
    int* blk_off  = wi;  wi += 1024;

    const int nblocks_scan = (n_nodes + SCAN_B - 1) / SCAN_B;

    // ---- CSR build (receivers constant across passes) ----
    hipMemsetAsync(cnt, 0, (size_t)n_nodes * sizeof(int), stream);
    hist_kernel<<<(n_edges + 255) / 256, 256, 0, stream>>>(receivers, n_edges, cnt);
    scan_block_kernel<<<nblocks_scan, SCAN_B, 0, stream>>>(cnt, n_nodes, scan_tmp, blk_sum);
    scan_top_kernel<<<1, 1024, 0, stream>>>(blk_sum, nblocks_scan, blk_off);
    scan_finalize_kernel<<<nblocks_scan, SCAN_B, 0, stream>>>(cnt, scan_tmp, blk_off,
                                                              n_nodes, row_ptr, running);
    fill_kernel<<<(n_edges + 255) / 256, 256, 0, stream>>>(receivers, n_edges, running, col_idx);

    const float* nodes_in = d_nodes;
    const float* glob_states[4] = { d_glob, gA, gB, out_glob };
    const int eb_grid = (n_edges + 255) / 256;
    const int nb_grid = (n_nodes + 255) / 256;
    const int consume_grid = n_graph * 16 + (n_nodes + 31) / 32;

    for (int pass = 0; pass < 3; ++pass) {
        float* nodes_out = (pass == 1) ? ws_nodes : out_nodes;

        node_proj_kernel<<<nb_grid, 256, 0, stream>>>(
            nodes_in,
            glob_states[pass == 0 ? 0 : pass - 1],
            pass == 0 ? nullptr : (float*)glob_states[pass],
            gsum_e, gsum_n,
            edge_gid, n_edges, node_gid, n_nodes,
            g_w1, g_b1, g_w2, g_b2, g_w3, g_b3,
            e_w1, e_b1, n_w1, n_b1,
            (__half*)nscratch, biasE, biasN, n_graph);

        if (pass == 0) {
            edge_block_kernel<false, true><<<eb_grid, 256, 0, stream>>>(
                d_edges, (const __half*)nscratch, biasE, senders, receivers, edge_gid,
                e_w1, e_w2, e_b2, e_w3, e_b3, eh0, n_edges);
            edge_consume_kernel<true><<<consume_grid, 256, 0, stream>>>(
                eh0, edge_gid, n_edges, gsum_e, col_idx, row_ptr, nscratch, n_nodes, n_graph);
        } else if (pass == 1) {
            edge_block_kernel<true, true><<<eb_grid, 256, 0, stream>>>(
                eh0, (const __half*)nscratch, biasE, senders, receivers, edge_gid,
                e_w1, e_w2, e_b2, e_w3, e_b3, eh1, n_edges);
            edge_consume_kernel<true><<<consume_grid, 256, 0, stream>>>(
                eh1, edge_gid, n_edges, gsum_e, col_idx, row_ptr, nscratch, n_nodes, n_graph);
        } else {
            edge_block_kernel<true, false><<<eb_grid, 256, 0, stream>>>(
                eh1, (const __half*)nscratch, biasE, senders, receivers, edge_gid,
                e_w1, e_w2, e_b2, e_w3, e_b3, out_edges, n_edges);
            edge_consume_kernel<false><<<consume_grid, 256, 0, stream>>>(
                out_edges, edge_gid, n_edges, gsum_e, col_idx, row_ptr, nscratch, n_nodes, n_graph);
        }

        node_block_kernel<<<nb_grid, 256, 0, stream>>>(
            nscratch, nodes_in, biasN, node_gid,
            n_w1, n_w2, n_b2, n_w3, n_b3,
            nodes_out, n_nodes);

        graph_sum_kernel<<<n_graph * 4, 256, 0, stream>>>(nodes_out, node_gid, n_nodes, gsum_n, 4);

        nodes_in = nodes_out;
    }

    // final global update (consumes pass-2 gsums + G_2) -> out_glob
    global_block_kernel<<<1, 64, 0, stream>>>(
        gsum_e, gsum_n, gB, edge_gid, n_edges, node_gid, n_nodes,
        g_w1, g_b1, g_w2, g_b2, g_w3, g_b3,
        out_glob, n_graph);
}

// Round 13
// 694.058 us; speedup vs baseline: 1.4047x; 1.4047x over previous
//
#include <hip/hip_runtime.h>
#include <hip/hip_fp16.h>

#define DEV_INLINE __device__ __forceinline__

static const int SCAN_B = 512;

DEV_INLINE int lower_bound_i(const int* __restrict__ a, int n, int v) {
    int lo = 0, hi = n;
    while (lo < hi) { int m = (lo + hi) >> 1; if (a[m] < v) lo = m + 1; else hi = m; }
    return lo;
}

// Bijective XCD-aware block swizzle (8 XCDs): block bid (dispatched to XCD
// bid%8) gets a contiguous chunk of the logical range. m204 formula.
DEV_INLINE int xcd_swizzle(int bid, int nb) {
    int xcd = bid & 7;
    int idx = bid >> 3;
    int q = nb >> 3, r = nb & 7;
    int base = (xcd < r) ? xcd * (q + 1) : r * (q + 1) + (xcd - r) * q;
    return base + idx;
}

// h[0:16] += 4 features * W rows (wave-uniform W -> scalar loads)
DEV_INLINE void fma4a(float (&h)[16], const float* __restrict__ W,
                      float a0, float a1, float a2, float a3) {
#pragma unroll
    for (int j = 0; j < 16; j++) h[j] = fmaf(a0, W[0 * 16 + j], h[j]);
#pragma unroll
    for (int j = 0; j < 16; j++) h[j] = fmaf(a1, W[1 * 16 + j], h[j]);
#pragma unroll
    for (int j = 0; j < 16; j++) h[j] = fmaf(a2, W[2 * 16 + j], h[j]);
#pragma unroll
    for (int j = 0; j < 16; j++) h[j] = fmaf(a3, W[3 * 16 + j], h[j]);
}
DEV_INLINE void fma4(float (&h)[16], const float* __restrict__ W, float4 a) {
    fma4a(h, W, a.x, a.y, a.z, a.w);
}

DEV_INLINE unsigned f2h2(float a, float b) {
    __half2 h = __floats2half2_rn(a, b);
    return *reinterpret_cast<unsigned*>(&h);
}
DEV_INLINE float2 h2f2(unsigned u) {
    __half2 h;
    *reinterpret_cast<unsigned*>(&h) = u;
    return __half22float2(h);
}
DEV_INLINE void unpack8(uint4 u, float* f) {
    float2 a = h2f2(u.x), b = h2f2(u.y), c = h2f2(u.z), d = h2f2(u.w);
    f[0]=a.x; f[1]=a.y; f[2]=b.x; f[3]=b.y; f[4]=c.x; f[5]=c.y; f[6]=d.x; f[7]=d.y;
}
DEV_INLINE uint4 pack8(const float* f) {
    return make_uint4(f2h2(f[0],f[1]), f2h2(f[2],f[3]), f2h2(f[4],f[5]), f2h2(f[6],f[7]));
}

// ========================= CSR build (once per launch) ======================
__global__ void hist_kernel(const int* __restrict__ receivers, int n_edges,
                            int* __restrict__ cnt) {
    int i = blockIdx.x * blockDim.x + threadIdx.x;
    if (i < n_edges) atomicAdd(&cnt[receivers[i]], 1);
}

__global__ __launch_bounds__(SCAN_B)
void scan_block_kernel(const int* __restrict__ cnt, int n,
                       int* __restrict__ scan_tmp, int* __restrict__ blk_sum) {
    __shared__ int s[SCAN_B];
    int tid = threadIdx.x;
    int i = blockIdx.x * SCAN_B + tid;
    int v = (i < n) ? cnt[i] : 0;
    s[tid] = v;
    __syncthreads();
    for (int off = 1; off < SCAN_B; off <<= 1) {
        int t = (tid >= off) ? s[tid - off] : 0;
        __syncthreads();
        s[tid] += t;
        __syncthreads();
    }
    if (i < n) scan_tmp[i] = s[tid];
    if (tid == SCAN_B - 1) blk_sum[blockIdx.x] = s[tid];
}

__global__ __launch_bounds__(1024)
void scan_top_kernel(int* __restrict__ blk_sum, int nb, int* __restrict__ blk_off) {
    __shared__ int s[1024];
    int tid = threadIdx.x;
    int v = (tid < nb) ? blk_sum[tid] : 0;
    s[tid] = v;
    __syncthreads();
    for (int off = 1; off < 1024; off <<= 1) {
        int t = (tid >= off) ? s[tid - off] : 0;
        __syncthreads();
        s[tid] += t;
        __syncthreads();
    }
    if (tid < nb) blk_off[tid] = s[tid] - v;   // exclusive
}

__global__ __launch_bounds__(SCAN_B)
void scan_finalize_kernel(const int* __restrict__ cnt, const int* __restrict__ scan_tmp,
                          const int* __restrict__ blk_off, int n,
                          int* __restrict__ row_ptr, int* __restrict__ running) {
    int i = blockIdx.x * SCAN_B + threadIdx.x;
    if (i >= n) return;
    int incl = scan_tmp[i] + blk_off[i / SCAN_B];
    row_ptr[i + 1] = incl;
    running[i] = incl - cnt[i];
    if (i == 0) row_ptr[0] = 0;
}

__global__ void fill_kernel(const int* __restrict__ receivers, int n_edges,
                            int* __restrict__ running, int* __restrict__ col_idx) {
    int e = blockIdx.x * blockDim.x + threadIdx.x;
    if (e >= n_edges) return;
    int pos = atomicAdd(&running[receivers[e]], 1);
    col_idx[pos] = e;
}

// ---- Per-pass precompute: node projections (f16) + fused global MLP --------
__global__ __launch_bounds__(256)
void node_proj_kernel(const float* __restrict__ nodes_in,
                      const float* __restrict__ glob_prev,
                      float* __restrict__ glob_cur,          // null on pass 0
                      float* __restrict__ gsum_e, float* __restrict__ gsum_n,
                      const int* __restrict__ edge_gid, int n_edges,
                      const int* __restrict__ node_gid, int n_nodes,
                      const float* __restrict__ gW1, const float* __restrict__ gB1,
                      const float* __restrict__ gW2, const float* __restrict__ gB2,
                      const float* __restrict__ gW3, const float* __restrict__ gB3,
                      const float* __restrict__ eW1, const float* __restrict__ eB1,
                      const float* __restrict__ nW1, const float* __restrict__ nB1,
                      __half* __restrict__ proj,
                      float* __restrict__ biasE, float* __restrict__ biasN,
                      int n_graph) {
    const int n0 = blockIdx.x * 256 + threadIdx.x;
    const int n  = min(n0, n_nodes - 1);
    const float4* pn = (const float4*)nodes_in + (size_t)n * 8;
    float4 xn[8];
#pragma unroll
    for (int q = 0; q < 8; q++) xn[q] = pn[q];

    float hr[16], hs[16];
#pragma unroll
    for (int j = 0; j < 16; j++) { hr[j] = 0.0f; hs[j] = 0.0f; }
#pragma unroll
    for (int q = 0; q < 8; q++) fma4(hr, eW1 + (32 + q * 4) * 16, xn[q]);
#pragma unroll
    for (int q = 0; q < 8; q++) fma4(hs, eW1 + (64 + q * 4) * 16, xn[q]);

    if (n0 < n_nodes) {
        uint4* po = (uint4*)(proj + (size_t)n0 * 32);
        po[0] = pack8(hr);
        po[1] = pack8(hr + 8);
        po[2] = pack8(hs);
        po[3] = pack8(hs + 8);
    }

    if (blockIdx.x == 0) {
        const int g = threadIdx.x;
        float gval[16];
        if (g < n_graph) {
            if (glob_cur) {
                int ecnt = lower_bound_i(edge_gid, n_edges, g + 1) - lower_bound_i(edge_gid, n_edges, g);
                int ncnt = lower_bound_i(node_gid, n_nodes, g + 1) - lower_bound_i(node_gid, n_nodes, g);
                float inv_e = 1.0f / fmaxf((float)ecnt, 1.0f);
                float inv_n = 1.0f / fmaxf((float)ncnt, 1.0f);
                float h1[16];
#pragma unroll
                for (int j = 0; j < 16; j++) h1[j] = gB1[j];
                float x[32];
#pragma unroll
                for (int q = 0; q < 8; q++) {
                    float4 v = ((const float4*)gsum_e)[(size_t)g * 8 + q];
                    x[q*4+0]=v.x*inv_e; x[q*4+1]=v.y*inv_e; x[q*4+2]=v.z*inv_e; x[q*4+3]=v.w*inv_e;
                }
#pragma unroll
                for (int k = 0; k < 32; k++)
#pragma unroll
                    for (int j = 0; j < 16; j++) h1[j] = fmaf(x[k], gW1[k * 16 + j], h1[j]);
#pragma unroll
                for (int q = 0; q < 8; q++) {
                    float4 v = ((const float4*)gsum_n)[(size_t)g * 8 + q];
                    x[q*4+0]=v.x*inv_n; x[q*4+1]=v.y*inv_n; x[q*4+2]=v.z*inv_n; x[q*4+3]=v.w*inv_n;
                }
#pragma unroll
                for (int k = 0; k < 32; k++)
#pragma unroll
                    for (int j = 0; j < 16; j++) h1[j] = fmaf(x[k], gW1[(32 + k) * 16 + j], h1[j]);
                float xg[16];
#pragma unroll
                for (int q = 0; q < 4; q++) {
                    float4 v = ((const float4*)glob_prev)[(size_t)g * 4 + q];
                    xg[q*4+0]=v.x; xg[q*4+1]=v.y; xg[q*4+2]=v.z; xg[q*4+3]=v.w;
                }
#pragma unroll
                for (int k = 0; k < 16; k++)
#pragma unroll
                    for (int j = 0; j < 16; j++) h1[j] = fmaf(xg[k], gW1[(64 + k) * 16 + j], h1[j]);
                float x2[16];
#pragma unroll
                for (int j = 0; j < 16; j++) x2[j] = fmaxf(h1[j], 0.0f);
                float h2[16];
#pragma unroll
                for (int j = 0; j < 16; j++) h2[j] = gB2[j];
#pragma unroll
                for (int k = 0; k < 16; k++)
#pragma unroll
                    for (int j = 0; j < 16; j++) h2[j] = fmaf(x2[k], gW2[k * 16 + j], h2[j]);
                float x3[16];
#pragma unroll
                for (int j = 0; j < 16; j++) x3[j] = fmaxf(h2[j], 0.0f);
#pragma unroll
                for (int j = 0; j < 16; j++) gval[j] = gB3[j];
#pragma unroll
                for (int k = 0; k < 16; k++)
#pragma unroll
                    for (int j = 0; j < 16; j++) gval[j] = fmaf(x3[k], gW3[k * 16 + j], gval[j]);
#pragma unroll
                for (int j = 0; j < 16; j++) glob_cur[g * 16 + j] = gval[j];
            } else {
#pragma unroll
                for (int j = 0; j < 16; j++) gval[j] = glob_prev[g * 16 + j];
            }
        }
        __syncthreads();   // gsum reads complete before zeroing
        for (int i = threadIdx.x; i < n_graph * 32; i += 256) {
            gsum_e[i] = 0.0f;
            gsum_n[i] = 0.0f;
        }
        if (g < n_graph) {
            float he[16], hn[16];
#pragma unroll
            for (int j = 0; j < 16; j++) { he[j] = eB1[j]; hn[j] = nB1[j]; }
#pragma unroll
            for (int k = 0; k < 16; k++)
#pragma unroll
                for (int j = 0; j < 16; j++) he[j] = fmaf(gval[k], eW1[(96 + k) * 16 + j], he[j]);
#pragma unroll
            for (int k = 0; k < 16; k++)
#pragma unroll
                for (int j = 0; j < 16; j++) hn[j] = fmaf(gval[k], nW1[(64 + k) * 16 + j], hn[j]);
#pragma unroll
            for (int j = 0; j < 16; j++) biasE[g * 16 + j] = he[j];
#pragma unroll
            for (int j = 0; j < 16; j++) biasN[g * 16 + j] = hn[j];
        }
    }
}

// ---------------- Edge block: 112 -> 16 -> 16 -> 32 (templated I/O) ---------
// XCD-swizzled block order: each XCD owns a contiguous edge span, so its L2
// only holds the proj rows of ~8 graphs instead of the whole table.
template<bool INH, bool OUTH>
__global__ __launch_bounds__(256)
void edge_block_kernel(const void* __restrict__ edges_in_v,
                       const __half* __restrict__ proj,
                       const float* __restrict__ biasE,
                       const int* __restrict__ senders,
                       const int* __restrict__ receivers,
                       const int* __restrict__ edge_gid,
                       const float* __restrict__ W1,
                       const float* __restrict__ W2, const float* __restrict__ B2,
                       const float* __restrict__ W3, const float* __restrict__ B3,
                       void* __restrict__ edges_out_v,
                       int n_edges) {
    const int sb = xcd_swizzle(blockIdx.x, gridDim.x);
    const int e0 = sb * 256 + threadIdx.x;
    const int e  = min(e0, n_edges - 1);

    const int rr = receivers[e], ss = senders[e], gg = edge_gid[e];

    float xe[32];
    if (INH) {
        const uint4* pe = (const uint4*)((const __half*)edges_in_v + (size_t)e * 32);
        uint4 u0 = pe[0], u1 = pe[1], u2 = pe[2], u3 = pe[3];
        unpack8(u0, xe); unpack8(u1, xe + 8); unpack8(u2, xe + 16); unpack8(u3, xe + 24);
    } else {
        const float4* pe = (const float4*)edges_in_v + (size_t)e * 8;
#pragma unroll
        for (int q = 0; q < 8; q++) {
            float4 v = pe[q];
            xe[q*4+0]=v.x; xe[q*4+1]=v.y; xe[q*4+2]=v.z; xe[q*4+3]=v.w;
        }
    }

    const uint4*  pr = (const uint4*)(proj + (size_t)rr * 32);        // halves [0:16)
    const uint4*  ps = (const uint4*)(proj + (size_t)ss * 32 + 16);   // halves [16:32)
    const float4* pb = (const float4*)biasE + (size_t)gg * 4;

    uint4 r0 = pr[0], r1 = pr[1];
    uint4 s0 = ps[0], s1 = ps[1];
    float4 xb[4];
#pragma unroll
    for (int q = 0; q < 4; q++) xb[q] = pb[q];

    float r[16], s[16];
    unpack8(r0, r); unpack8(r1, r + 8);
    unpack8(s0, s); unpack8(s1, s + 8);

    float h1[16];
#pragma unroll
    for (int q = 0; q < 4; q++) {
        h1[q*4+0] = xb[q].x + r[q*4+0] + s[q*4+0];
        h1[q*4+1] = xb[q].y + r[q*4+1] + s[q*4+1];
        h1[q*4+2] = xb[q].z + r[q*4+2] + s[q*4+2];
        h1[q*4+3] = xb[q].w + r[q*4+3] + s[q*4+3];
    }
#pragma unroll
    for (int q = 0; q < 8; q++)
        fma4a(h1, W1 + (q * 4) * 16, xe[q*4+0], xe[q*4+1], xe[q*4+2], xe[q*4+3]);

    float x2[16];
#pragma unroll
    for (int j = 0; j < 16; j++) x2[j] = fmaxf(h1[j], 0.0f);
    float h2[16];
#pragma unroll
    for (int j = 0; j < 16; j++) h2[j] = B2[j];
#pragma unroll
    for (int k = 0; k < 16; k++)
#pragma unroll
        for (int j = 0; j < 16; j++) h2[j] = fmaf(x2[k], W2[k * 16 + j], h2[j]);

    float x3[16];
#pragma unroll
    for (int j = 0; j < 16; j++) x3[j] = fmaxf(h2[j], 0.0f);
    float o[32];
#pragma unroll
    for (int j = 0; j < 32; j++) o[j] = B3[j];
#pragma unroll
    for (int k = 0; k < 16; k++)
#pragma unroll
        for (int j = 0; j < 32; j++)
            o[j] = fmaf(x3[k], W3[k * 32 + j], o[j]);

    if (e0 < n_edges) {
        if (OUTH) {
            uint4* eo = (uint4*)((__half*)edges_out_v + (size_t)e0 * 32);
            eo[0] = pack8(o); eo[1] = pack8(o + 8); eo[2] = pack8(o + 16); eo[3] = pack8(o + 24);
        } else {
            float4* eo = (float4*)edges_out_v + (size_t)e0 * 8;
#pragma unroll
            for (int j4 = 0; j4 < 8; j4++)
                eo[j4] = make_float4(o[j4*4+0], o[j4*4+1], o[j4*4+2], o[j4*4+3]);
        }
    }
}

// -------- Fused edge-consumer: per-graph sums + CSR receiver aggregation ----
// Blocks [0, n_graph*16): graph-sum role (sorted gid ranges).
// Blocks [n_graph*16, ...): agg role (8 lanes per node via CSR).
template<bool INH>
__global__ __launch_bounds__(256)
void edge_consume_kernel(const void* __restrict__ edges_data_v,
                         const int* __restrict__ gid, int n_edges,
                         float* __restrict__ gsum,
                         const int* __restrict__ col_idx,
                         const int* __restrict__ row_ptr,
                         float* __restrict__ agg_mean, int n_nodes, int n_graph) {
    __shared__ float red[256];
    const int GS_BLOCKS = n_graph * 16;

    if ((int)blockIdx.x < GS_BLOCKS) {
        int g = blockIdx.x >> 4;
        int s = blockIdx.x & 15;
        int lo = lower_bound_i(gid, n_edges, g);
        int hi = lower_bound_i(gid, n_edges, g + 1);
        int len = hi - lo;
        int chunk = (len + 15) / 16;
        int rlo = lo + s * chunk;
        int rhi = min(rlo + chunk, hi);

        int c = threadIdx.x & 31;
        int rg = threadIdx.x >> 5;   // 8 row-groups
        float acc = 0.0f;
        for (int r = rlo + rg; r < rhi; r += 8) {
            if (INH) acc += __half2float(((const __half*)edges_data_v)[(size_t)r * 32 + c]);
            else     acc += ((const float*)edges_data_v)[(size_t)r * 32 + c];
        }
        red[threadIdx.x] = acc;
        __syncthreads();
        if (threadIdx.x < 32) {
            float ssum = 0.0f;
#pragma unroll
            for (int i = 0; i < 8; i++) ssum += red[i * 32 + threadIdx.x];
            atomicAdd(&gsum[g * 32 + threadIdx.x], ssum);
        }
    } else {
        int bb = blockIdx.x - GS_BLOCKS;
        int node = bb * 32 + (threadIdx.x >> 3);
        int lane = threadIdx.x & 7;
        if (node >= n_nodes) return;
        int lo = row_ptr[node], hi = row_ptr[node + 1];
        float4 acc = make_float4(0.f, 0.f, 0.f, 0.f);
        for (int e = lo; e < hi; e++) {
            int idx = col_idx[e];
            if (INH) {
                uint2 u = *(const uint2*)((const __half*)edges_data_v + (size_t)idx * 32 + lane * 4);
                float2 a = h2f2(u.x), b = h2f2(u.y);
                acc.x += a.x; acc.y += a.y; acc.z += b.x; acc.w += b.y;
            } else {
                float4 v = ((const float4*)((const float*)edges_data_v + (size_t)idx * 32))[lane];
                acc.x += v.x; acc.y += v.y; acc.z += v.z; acc.w += v.w;
            }
        }
        float inv = 1.0f / fmaxf((float)(hi - lo), 1.0f);
        ((float4*)(agg_mean + (size_t)node * 32))[lane] =
            make_float4(acc.x * inv, acc.y * inv, acc.z * inv, acc.w * inv);
    }
}

// ---------------- Node block: 80 -> 16 -> 16 -> 32 --------------------------
__global__ __launch_bounds__(256)
void node_block_kernel(const float* __restrict__ agg_mean,
                       const float* __restrict__ nodes_in,
                       const float* __restrict__ biasN,
                       const int* __restrict__ node_gid,
                       const float* __restrict__ W1,
                       const float* __restrict__ W2, const float* __restrict__ B2,
                       const float* __restrict__ W3, const float* __restrict__ B3,
                       float* __restrict__ nodes_out,
                       int n_nodes) {
    const int n0 = blockIdx.x * 256 + threadIdx.x;
    const int n  = min(n0, n_nodes - 1);
    const int gg = node_gid[n];

    const float4* pa = (const float4*)agg_mean + (size_t)n * 8;
    const float4* pn = (const float4*)nodes_in + (size_t)n * 8;
    const float4* pb = (const float4*)biasN + (size_t)gg * 4;

    float4 xa[8], xn[8], xb[4];
#pragma unroll
    for (int q = 0; q < 8; q++) xa[q] = pa[q];
#pragma unroll
    for (int q = 0; q < 8; q++) xn[q] = pn[q];
#pragma unroll
    for (int q = 0; q < 4; q++) xb[q] = pb[q];

    float h1[16];
#pragma unroll
    for (int q = 0; q < 4; q++) {
        h1[q*4+0] = xb[q].x; h1[q*4+1] = xb[q].y; h1[q*4+2] = xb[q].z; h1[q*4+3] = xb[q].w;
    }
#pragma unroll
    for (int q = 0; q < 8; q++) fma4(h1, W1 + (q * 4) * 16, xa[q]);
#pragma unroll
    for (int q = 0; q < 8; q++) fma4(h1, W1 + (32 + q * 4) * 16, xn[q]);

    float x2[16];
#pragma unroll
    for (int j = 0; j < 16; j++) x2[j] = fmaxf(h1[j], 0.0f);
    float h2[16];
#pragma unroll
    for (int j = 0; j < 16; j++) h2[j] = B2[j];
#pragma unroll
    for (int k = 0; k < 16; k++)
#pragma unroll
        for (int j = 0; j < 16; j++) h2[j] = fmaf(x2[k], W2[k * 16 + j], h2[j]);

    float x3[16];
#pragma unroll
    for (int j = 0; j < 16; j++) x3[j] = fmaxf(h2[j], 0.0f);
    float o[32];
#pragma unroll
    for (int j = 0; j < 32; j++) o[j] = B3[j];
#pragma unroll
    for (int k = 0; k < 16; k++)
#pragma unroll
        for (int j = 0; j < 32; j++)
            o[j] = fmaf(x3[k], W3[k * 32 + j], o[j]);

    if (n0 < n_nodes) {
        float4* no = (float4*)(nodes_out + (size_t)n0 * 32);
#pragma unroll
        for (int j4 = 0; j4 < 8; j4++)
            no[j4] = make_float4(o[j4*4+0], o[j4*4+1], o[j4*4+2], o[j4*4+3]);
    }
}

// ---------------- Per-graph sums over sorted gid ranges (node side) ---------
__global__ __launch_bounds__(256)
void graph_sum_kernel(const float* __restrict__ x, const int* __restrict__ gid,
                      int n_rows, float* __restrict__ sums, int splits) {
    int g = blockIdx.x / splits;
    int s = blockIdx.x % splits;
    int lo = lower_bound_i(gid, n_rows, g);
    int hi = lower_bound_i(gid, n_rows, g + 1);
    int len = hi - lo;
    int chunk = (len + splits - 1) / splits;
    int rlo = lo + s * chunk;
    int rhi = min(rlo + chunk, hi);

    int c = threadIdx.x & 31;
    int rg = threadIdx.x >> 5;
    float acc = 0.0f;
    for (int r = rlo + rg; r < rhi; r += 8)
        acc += x[(size_t)r * 32 + c];

    __shared__ float red[256];
    red[threadIdx.x] = acc;
    __syncthreads();
    if (threadIdx.x < 32) {
        float ssum = 0.0f;
#pragma unroll
        for (int i = 0; i < 8; i++) ssum += red[i * 32 + threadIdx.x];
        atomicAdd(&sums[g * 32 + threadIdx.x], ssum);
    }
}

// ---------------- Global block (final pass only) -----------------------------
__global__ __launch_bounds__(64)
void global_block_kernel(const float* __restrict__ gsum_e,
                         const float* __restrict__ gsum_n,
                         const float* __restrict__ glob_in,
                         const int* __restrict__ edge_gid, int n_edges,
                         const int* __restrict__ node_gid, int n_nodes,
                         const float* __restrict__ W1, const float* __restrict__ B1,
                         const float* __restrict__ W2, const float* __restrict__ B2,
                         const float* __restrict__ W3, const float* __restrict__ B3,
                         float* __restrict__ glob_out, int n_graph) {
    const int g0 = threadIdx.x;
    const int g  = min(g0, n_graph - 1);

    int ecnt = lower_bound_i(edge_gid, n_edges, g + 1) - lower_bound_i(edge_gid, n_edges, g);
    int ncnt = lower_bound_i(node_gid, n_nodes, g + 1) - lower_bound_i(node_gid, n_nodes, g);
    float inv_e = 1.0f / fmaxf((float)ecnt, 1.0f);
    float inv_n = 1.0f / fmaxf((float)ncnt, 1.0f);

    float h1[16];
#pragma unroll
    for (int j = 0; j < 16; j++) h1[j] = B1[j];

    {
        float x[32];
#pragma unroll
        for (int q = 0; q < 8; q++) {
            float4 v = ((const float4*)gsum_e)[(size_t)g * 8 + q];
            x[q*4+0]=v.x*inv_e; x[q*4+1]=v.y*inv_e; x[q*4+2]=v.z*inv_e; x[q*4+3]=v.w*inv_e;
        }
#pragma unroll
        for (int k = 0; k < 32; k++)
#pragma unroll
            for (int j = 0; j < 16; j++) h1[j] = fmaf(x[k], W1[k * 16 + j], h1[j]);
#pragma unroll
        for (int q = 0; q < 8; q++) {
            float4 v = ((const float4*)gsum_n)[(size_t)g * 8 + q];
            x[q*4+0]=v.x*inv_n; x[q*4+1]=v.y*inv_n; x[q*4+2]=v.z*inv_n; x[q*4+3]=v.w*inv_n;
        }
#pragma unroll
        for (int k = 0; k < 32; k++)
#pragma unroll
            for (int j = 0; j < 16; j++) h1[j] = fmaf(x[k], W1[(32 + k) * 16 + j], h1[j]);
    }
    {
        float xg[16];
#pragma unroll
        for (int q = 0; q < 4; q++) {
            float4 v = ((const float4*)glob_in)[(size_t)g * 4 + q];
            xg[q*4+0]=v.x; xg[q*4+1]=v.y; xg[q*4+2]=v.z; xg[q*4+3]=v.w;
        }
#pragma unroll
        for (int k = 0; k < 16; k++)
#pragma unroll
            for (int j = 0; j < 16; j++) h1[j] = fmaf(xg[k], W1[(64 + k) * 16 + j], h1[j]);
    }

    float x2[16];
#pragma unroll
    for (int j = 0; j < 16; j++) x2[j] = fmaxf(h1[j], 0.0f);
    float h2[16];
#pragma unroll
    for (int j = 0; j < 16; j++) h2[j] = B2[j];
#pragma unroll
    for (int k = 0; k < 16; k++)
#pragma unroll
        for (int j = 0; j < 16; j++) h2[j] = fmaf(x2[k], W2[k * 16 + j], h2[j]);

    float x3[16];
#pragma unroll
    for (int j = 0; j < 16; j++) x3[j] = fmaxf(h2[j], 0.0f);
    float o[16];
#pragma unroll
    for (int j = 0; j < 16; j++) o[j] = B3[j];
#pragma unroll
    for (int k = 0; k < 16; k++)
#pragma unroll
        for (int j = 0; j < 16; j++) o[j] = fmaf(x3[k], W3[k * 16 + j], o[j]);

    if (g0 < n_graph) {
#pragma unroll
        for (int j = 0; j < 16; j++) glob_out[g0 * 16 + j] = o[j];
    }
}

extern "C" void kernel_launch(void* const* d_in, const int* in_sizes, int n_in,
                              void* d_out, int out_size, void* d_ws, size_t ws_size,
                              hipStream_t stream) {
    const float* d_nodes = (const float*)d_in[0];
    const float* d_edges = (const float*)d_in[1];
    const float* d_glob  = (const float*)d_in[2];
    const int* senders   = (const int*)d_in[3];
    const int* receivers = (const int*)d_in[4];
    const int* node_gid  = (const int*)d_in[5];
    const int* edge_gid  = (const int*)d_in[6];
    const float* e_w1 = (const float*)d_in[7];
    const float* e_b1 = (const float*)d_in[8];
    const float* e_w2 = (const float*)d_in[9];
    const float* e_b2 = (const float*)d_in[10];
    const float* e_w3 = (const float*)d_in[11];
    const float* e_b3 = (const float*)d_in[12];
    const float* n_w1 = (const float*)d_in[13];
    const float* n_b1 = (const float*)d_in[14];
    const float* n_w2 = (const float*)d_in[15];
    const float* n_b2 = (const float*)d_in[16];
    const float* n_w3 = (const float*)d_in[17];
    const float* n_b3 = (const float*)d_in[18];
    const float* g_w1 = (const float*)d_in[19];
    const float* g_b1 = (const float*)d_in[20];
    const float* g_w2 = (const float*)d_in[21];
    const float* g_b2 = (const float*)d_in[22];
    const float* g_w3 = (const float*)d_in[23];
    const float* g_b3 = (const float*)d_in[24];

    const int n_nodes = in_sizes[0] / 32;
    const int n_edges = in_sizes[1] / 32;
    const int n_graph = in_sizes[2] / 16;

    float* out_nodes = (float*)d_out;                        // n_nodes*32
    float* out_edges = out_nodes + (size_t)n_nodes * 32;     // n_edges*32
    float* out_glob  = out_edges + (size_t)n_edges * 32;     // n_graph*16

    float* ws = (float*)d_ws;
    float* ws_edges = ws;  ws += (size_t)n_edges * 32;       // reused as 2x f16 edge buffers
    float* ws_nodes = ws;  ws += (size_t)n_nodes * 32;
    float* nscratch = ws;  ws += (size_t)n_nodes * 32;       // proj(f16) THEN agg_mean(f32)
    float* gA       = ws;  ws += (size_t)n_graph * 16;
    float* gB       = ws;  ws += (size_t)n_graph * 16;
    float* gsum_e   = ws;  ws += (size_t)n_graph * 32;
    float* gsum_n   = ws;  ws += (size_t)n_graph * 32;
    float* biasE    = ws;  ws += (size_t)n_graph * 16;
    float* biasN    = ws;  ws += (size_t)n_graph * 16;

    __half* eh0 = (__half*)ws_edges;                         // n_edges*32 halves
    __half* eh1 = eh0 + (size_t)n_edges * 32;                // n_edges*32 halves

    int* wi = (int*)ws;
    int* cnt      = wi;  wi += n_nodes;
    int* row_ptr  = wi;  wi += n_nodes + 1;
    int* running  = wi;  wi += n_nodes;
    int* scan_tmp = wi;  wi += n_nodes;
    int* col_idx  = wi;  wi += n_edges;
    int* blk_sum  = wi;  wi += 1024;
    int* blk_off  = wi;  wi += 1024;

    const int nblocks_scan = (n_nodes + SCAN_B - 1) / SCAN_B;

    // ---- CSR build (receivers constant across passes) ----
    hipMemsetAsync(cnt, 0, (size_t)n_nodes * sizeof(int), stream);
    hist_kernel<<<(n_edges + 255) / 256, 256, 0, stream>>>(receivers, n_edges, cnt);
    scan_block_kernel<<<nblocks_scan, SCAN_B, 0, stream>>>(cnt, n_nodes, scan_tmp, blk_sum);
    scan_top_kernel<<<1, 1024, 0, stream>>>(blk_sum, nblocks_scan, blk_off);
    scan_finalize_kernel<<<nblocks_scan, SCAN_B, 0, stream>>>(cnt, scan_tmp, blk_off,
                                                              n_nodes, row_ptr, running);
    fill_kernel<<<(n_edges + 255) / 256, 256, 0, stream>>>(receivers, n_edges, running, col_idx);

    const float* nodes_in = d_nodes;
    const float* glob_states[4] = { d_glob, gA, gB, out_glob };
    const int eb_grid = (n_edges + 255) / 256;
    const int nb_grid = (n_nodes + 255) / 256;
    const int consume_grid = n_graph * 16 + (n_nodes + 31) / 32;

    for (int pass = 0; pass < 3; ++pass) {
        float* nodes_out = (pass == 1) ? ws_nodes : out_nodes;

        node_proj_kernel<<<nb_grid, 256, 0, stream>>>(
            nodes_in,
            glob_states[pass == 0 ? 0 : pass - 1],
            pass == 0 ? nullptr : (float*)glob_states[pass],
            gsum_e, gsum_n,
            edge_gid, n_edges, node_gid, n_nodes,
            g_w1, g_b1, g_w2, g_b2, g_w3, g_b3,
            e_w1, e_b1, n_w1, n_b1,
            (__half*)nscratch, biasE, biasN, n_graph);

        if (pass == 0) {
            edge_block_kernel<false, true><<<eb_grid, 256, 0, stream>>>(
                d_edges, (const __half*)nscratch, biasE, senders, receivers, edge_gid,
                e_w1, e_w2, e_b2, e_w3, e_b3, eh0, n_edges);
            edge_consume_kernel<true><<<consume_grid, 256, 0, stream>>>(
                eh0, edge_gid, n_edges, gsum_e, col_idx, row_ptr, nscratch, n_nodes, n_graph);
        } else if (pass == 1) {
            edge_block_kernel<true, true><<<eb_grid, 256, 0, stream>>>(
                eh0, (const __half*)nscratch, biasE, senders, receivers, edge_gid,
                e_w1, e_w2, e_b2, e_w3, e_b3, eh1, n_edges);
            edge_consume_kernel<true><<<consume_grid, 256, 0, stream>>>(
                eh1, edge_gid, n_edges, gsum_e, col_idx, row_ptr, nscratch, n_nodes, n_graph);
        } else {
            edge_block_kernel<true, false><<<eb_grid, 256, 0, stream>>>(
                eh1, (const __half*)nscratch, biasE, senders, receivers, edge_gid,
                e_w1, e_w2, e_b2, e_w3, e_b3, out_edges, n_edges);
            edge_consume_kernel<false><<<consume_grid, 256, 0, stream>>>(
                out_edges, edge_gid, n_edges, gsum_e, col_idx, row_ptr, nscratch, n_nodes, n_graph);
        }

        node_block_kernel<<<nb_grid, 256, 0, stream>>>(
            nscratch, nodes_in, biasN, node_gid,
            n_w1, n_w2, n_b2, n_w3, n_b3,
            nodes_out, n_nodes);

        graph_sum_kernel<<<n_graph * 4, 256, 0, stream>>>(nodes_out, node_gid, n_nodes, gsum_n, 4);

        nodes_in = nodes_out;
    }

    // final global update (consumes pass-2 gsums + G_2) -> out_glob
    global_block_kernel<<<1, 64, 0, stream>>>(
        gsum_e, gsum_n, gB, edge_gid, n_edges, node_gid, n_nodes,
        g_w1, g_b1, g_w2, g_b2, g_w3, g_b3,
        out_glob, n_graph);
}